// Round 4
// baseline (874.857 us; speedup 1.0000x reference)
//
#include <hip/hip_runtime.h>

// Upsample2d (upfirdn2d, factor=2, down=1, k=[1,3,1] outer, gain*factor^2=4).
// Validated index algebra (rounds 1-3, absmax 3.1e-2):
//   out[n, c2, h2, w2] = sum_{u,v in 0..2} K[u][v] * T(ab=h2+u-2, bb=w2+v-2)
//   T nonzero iff ab,bb in [0,510] AND in odd 128-block ((x>>7)&1), then
//   T = x_n[(2*c2 + (ab>>8))*32768 + (ab&127)*256 + (bb>>8)*128 + (bb&127)]
//
// ROUND 4 = DIAGNOSTIC ROUND. Real kernel unchanged (R3). Two padded probe
// kernels (write d_ws only) run long enough (~400us) to surface in the
// rocprof top-5 with FETCH_SIZE/WRITE_SIZE for the real access pattern.
// diagA = full load+store pattern clone; diagB = store-pattern only.

__device__ __forceinline__ void pad_chain(float seed, int iters) {
    float v = seed;
#pragma unroll 16
    for (int it = 0; it < iters; ++it) v = fmaf(v, 1.0000002f, 1e-8f);
    asm volatile("" :: "v"(v));   // keep chain live, no side effects
}

template <int PAD>
__device__ __forceinline__ void upfir_body(const float* __restrict__ x,
                                           float* __restrict__ out) {
    const unsigned t  = blockIdx.x * 256u + threadIdx.x;
    const unsigned i  = t & 127u;
    const unsigned g  = (t >> 7) & 127u;
    const unsigned c2 = (t >> 14) & 127u;
    const unsigned n  = t >> 21;

    const float* __restrict__ xn = x + (size_t)n * 8388608u;

    const int BL = (int)(i << 2) - 4;
    const int BC = (int)(i << 2);
    const bool vL = (BL >= 0) && (((BL >> 7) & 1) != 0);
    const bool vC = (((BC >> 7) & 1) != 0);
    const int offL = ((BL >> 8) << 7) + (BL & 127);
    const int offC = ((BC >> 8) << 7) + (BC & 127);

    const float KE = 4.f / 25.f, KM = 12.f / 25.f, KC = 36.f / 25.f;

    float acc[4][4] = {};
    const int ab0 = (int)(g << 2) - 2;

#pragma unroll
    for (int j = 0; j < 6; ++j) {
        const int ab = ab0 + j;
        if ((unsigned)ab > 510u) continue;
        if (((ab >> 7) & 1) == 0) continue;
        const float* __restrict__ base =
            xn + (((size_t)(2u * c2 + (unsigned)(ab >> 8))) << 15)
               + (size_t)((ab & 127) << 8);

        float4 xl = vL ? *reinterpret_cast<const float4*>(base + offL)
                       : make_float4(0.f, 0.f, 0.f, 0.f);
        float4 xc = vC ? *reinterpret_cast<const float4*>(base + offC)
                       : make_float4(0.f, 0.f, 0.f, 0.f);
        if (i == 127u) xc.w = 0.f;

        const float t0 = xl.z, t1 = xl.w, t2 = xc.x,
                    t3 = xc.y, t4 = xc.z, t5 = xc.w;
        const float s0 = t0 + t2, s1 = t1 + t3, s2 = t2 + t4, s3 = t3 + t5;

#pragma unroll
        for (int u = 0; u < 3; ++u) {
            const int r = j - u;
            if (r < 0 || r > 3) continue;
            const float w0 = (u == 1) ? KM : KE;
            const float w1 = (u == 1) ? KC : KM;
            acc[r][0] += w0 * s0 + w1 * t1;
            acc[r][1] += w0 * s1 + w1 * t2;
            acc[r][2] += w0 * s2 + w1 * t3;
            acc[r][3] += w0 * s3 + w1 * t4;
        }
    }

    if (PAD > 0) pad_chain(acc[0][0] + acc[3][3] + (float)i, PAD);

    float4* __restrict__ oq = reinterpret_cast<float4*>(out)
        + ((((size_t)((n << 7) + c2) << 9) + (size_t)(g << 2)) << 7) + i;
#pragma unroll
    for (int r = 0; r < 4; ++r)
        oq[(size_t)r << 7] = make_float4(acc[r][0], acc[r][1], acc[r][2], acc[r][3]);
}

__global__ __launch_bounds__(256) void upfir2x_kernel(const float* __restrict__ x,
                                                      float* __restrict__ out) {
    upfir_body<0>(x, out);
}

// diagA: identical loads + identical store pattern, but into ws.
__global__ __launch_bounds__(256) void diagA_pattern_probe(const float* __restrict__ x,
                                                           float* __restrict__ ws) {
    upfir_body<2048>(x, ws);
}

// diagB: store pattern only (no input reads).
__global__ __launch_bounds__(256) void diagB_store_probe(float* __restrict__ ws) {
    const unsigned t  = blockIdx.x * 256u + threadIdx.x;
    const unsigned i  = t & 127u;
    const unsigned g  = (t >> 7) & 127u;
    const unsigned c2 = (t >> 14) & 127u;
    const unsigned n  = t >> 21;

    pad_chain((float)t, 3072);

    float4* __restrict__ oq = reinterpret_cast<float4*>(ws)
        + ((((size_t)((n << 7) + c2) << 9) + (size_t)(g << 2)) << 7) + i;
#pragma unroll
    for (int r = 0; r < 4; ++r)
        oq[(size_t)r << 7] = make_float4(0.f, 0.f, 0.f, 0.f);
}

extern "C" void kernel_launch(void* const* d_in, const int* in_sizes, int n_in,
                              void* d_out, int out_size, void* d_ws, size_t ws_size,
                              hipStream_t stream) {
    const float* x   = (const float*)d_in[0];
    float*       out = (float*)d_out;
    const unsigned nthreads = (unsigned)(out_size / 16);   // 8388608
    dim3 grid(nthreads / 256u), block(256u);

    hipLaunchKernelGGL(upfir2x_kernel, grid, block, 0, stream, x, out);

    // Diagnostic probes: only touch scratch; need out_size floats of ws.
    if (ws_size >= (size_t)out_size * sizeof(float)) {
        float* ws = (float*)d_ws;
        hipLaunchKernelGGL(diagA_pattern_probe, grid, block, 0, stream, x, ws);
        hipLaunchKernelGGL(diagB_store_probe,   grid, block, 0, stream, ws);
    }
}

// Round 6
// 110.006 us; speedup vs baseline: 7.9528x; 7.9528x over previous
//
#include <hip/hip_runtime.h>

// Upsample2d (upfirdn2d, factor=2, down=1, k=[1,3,1] outer, gain*factor^2=4).
// Validated index algebra (rounds 1-3, absmax 3.1e-2):
//   out[n, c2, h2, w2] = sum_{u,v in 0..2} K[u][v] * T(ab=h2+u-2, bb=w2+v-2)
//   T nonzero iff ab,bb in [0,510] AND in odd 128-block ((x>>7)&1), then
//   T = x_n[(2*c2 + (ab>>8))*32768 + (ab&127)*256 + (bb>>8)*128 + (bb&127)]
//   K = [[1,3,1],[3,9,3],[1,3,1]] * 4/25.
//
// Round-4 diagnostics: store pattern ideal (WRITE_SIZE=537MB, no RMW, FETCH~0).
// Round-6 = round-5 retry with a compile fix: __builtin_nontemporal_store
// needs a native clang vector type, not HIP's float4 class. NT stores keep
// the 512MB write-once stream from evicting the (128MB, 6x-reused) input
// from L2/L3.

typedef float vfloat4 __attribute__((ext_vector_type(4)));

__global__ __launch_bounds__(256) void upfir2x_kernel(const float* __restrict__ x,
                                                      float* __restrict__ out) {
    const unsigned t  = blockIdx.x * 256u + threadIdx.x;
    const unsigned i  = t & 127u;           // column quad within row (w2 = 4i)
    const unsigned g  = (t >> 7) & 127u;    // row group: output rows 4g..4g+3
    const unsigned c2 = (t >> 14) & 127u;
    const unsigned n  = t >> 21;

    const float* __restrict__ xn = x + (size_t)n * 8388608u;

    // Column taps bb = 4i-2 .. 4i+3 live in 4-aligned quads BL=4i-4, BC=4i;
    // validity is per-quad uniform (128 | block period).
    const int BL = (int)(i << 2) - 4;
    const int BC = (int)(i << 2);
    const bool vL = (BL >= 0) && (((BL >> 7) & 1) != 0);
    const bool vC = (((BC >> 7) & 1) != 0);
    const int offL = ((BL >> 8) << 7) + (BL & 127);   // (B>>8)*128 + (B&127)
    const int offC = ((BC >> 8) << 7) + (BC & 127);

    const float KE = 4.f / 25.f;    // corner
    const float KM = 12.f / 25.f;   // edge
    const float KC = 36.f / 25.f;   // center

    float acc[4][4] = {};
    const int ab0 = (int)(g << 2) - 2;      // first tap row

#pragma unroll
    for (int j = 0; j < 6; ++j) {
        const int ab = ab0 + j;
        if ((unsigned)ab > 510u) continue;        // wave-uniform skip
        if (((ab >> 7) & 1) == 0) continue;       // even block -> zero-stuffed
        const float* __restrict__ base =
            xn + (((size_t)(2u * c2 + (unsigned)(ab >> 8))) << 15)
               + (size_t)((ab & 127) << 8);

        vfloat4 xl = vL ? *reinterpret_cast<const vfloat4*>(base + offL)
                        : (vfloat4){0.f, 0.f, 0.f, 0.f};
        vfloat4 xc = vC ? *reinterpret_cast<const vfloat4*>(base + offC)
                        : (vfloat4){0.f, 0.f, 0.f, 0.f};
        if (i == 127u) xc.w = 0.f;                // bb = 511 out of range

        const float t0 = xl.z, t1 = xl.w, t2 = xc.x,
                    t3 = xc.y, t4 = xc.z, t5 = xc.w;
        const float s0 = t0 + t2, s1 = t1 + t3, s2 = t2 + t4, s3 = t3 + t5;

#pragma unroll
        for (int u = 0; u < 3; ++u) {
            const int r = j - u;                  // output row in the group
            if (r < 0 || r > 3) continue;
            const float w0 = (u == 1) ? KM : KE;  // K[u][0] == K[u][2]
            const float w1 = (u == 1) ? KC : KM;  // K[u][1]
            acc[r][0] += w0 * s0 + w1 * t1;
            acc[r][1] += w0 * s1 + w1 * t2;
            acc[r][2] += w0 * s2 + w1 * t3;
            acc[r][3] += w0 * s3 + w1 * t4;
        }
    }

    // Nontemporal stores: write-once stream, keep it out of L2/L3.
    vfloat4* __restrict__ oq = reinterpret_cast<vfloat4*>(out)
        + ((((size_t)((n << 7) + c2) << 9) + (size_t)(g << 2)) << 7) + i;
#pragma unroll
    for (int r = 0; r < 4; ++r) {
        vfloat4 v = {acc[r][0], acc[r][1], acc[r][2], acc[r][3]};
        __builtin_nontemporal_store(v, oq + ((size_t)r << 7));
    }
}

extern "C" void kernel_launch(void* const* d_in, const int* in_sizes, int n_in,
                              void* d_out, int out_size, void* d_ws, size_t ws_size,
                              hipStream_t stream) {
    const float* x   = (const float*)d_in[0];
    float*       out = (float*)d_out;
    const unsigned nthreads = (unsigned)(out_size / 16);   // 8388608
    dim3 grid(nthreads / 256u), block(256u);
    hipLaunchKernelGGL(upfir2x_kernel, grid, block, 0, stream, x, out);
}